// Round 3
// baseline (299.457 us; speedup 1.0000x reference)
//
#include <hip/hip_runtime.h>
#include <math.h>

// MambaBlock, fp32 in/out, bf16 MFMA compute.
// uv = x @ Wi^T + bi ; u,v = split(uv) ; y = silu(dwconv3(v)+bc)*u ; out = y @ Wo^T + bo
// B=4, L=4096, D=1024 -> M = 16384 rows; GEMM1 N=2048, GEMM2 N=1024, K=1024.
//
// GEMM v4 (register-pipelined): 256x256 tile, BK=32, 512 threads (8 waves,
// 2M x 4N), ring of 4 LDS slots (128 KiB), prefetch depth ~2 tiles staged +
// 1 tile of fragments in registers.  Per K-tile t:
//   top:  vmcnt(4) [retires tile t+1's loads]  +  ONE s_barrier
//   ph0:  stage A(t+3) | read av1_t | MFMA acc[0..3] on (a0_t, bvv_t)  <- regs
//         loaded during tile t-1, so no lgkm stall
//   ph1:  stage B(t+3) | prefetch (bvv,a0)_{t+1} from slot (t+1)&3 |
//         MFMA acc[4..7] on (av1_t, bvv_t)
// NO explicit lgkmcnt / sched_barrier: the compiler emits counted
// lgkmcnt(8/4) and interleaves ds_read under MFMA issue (R2's explicit
// lgkmcnt(0)+sched_barrier(0) fence serialized LDS bursts against MFMA
// bursts -> 30% MfmaUtil).  Race-freedom: slot (t+3)&3 = (t-1)&3's last
// readers (av1_{t-1} in t-1 ph0, prefetch in t-2 ph1) completed before
// their consuming MFMAs issued, hence before those waves crossed tile t's
// top barrier; vmcnt precedes the barrier so every wave's staging loads for
// slot s are retired chip-wide before any wave reads slot s.
//
// LDS swizzle (64B rows, 4x16B groups): logical group g of row r stored at
// physical g ^ ((r>>1)&3); staging pre-swizzles the GLOBAL source address
// (linear LDS dest for global_load_lds), ds_read applies the same XOR.
// T1 XCD swizzle: each XCD owns a contiguous M-chunk (FETCH 135->49 MB).

typedef __attribute__((ext_vector_type(8))) short short8;
typedef __attribute__((ext_vector_type(4))) float floatx4;

__device__ __forceinline__ float b2f(short s) {
    unsigned int u = ((unsigned int)(unsigned short)s) << 16;
    float f;
    __builtin_memcpy(&f, &u, 4);
    return f;
}

__device__ __forceinline__ short f2b(float f) {
    unsigned int u;
    __builtin_memcpy(&u, &f, 4);
    u += 0x7fffu + ((u >> 16) & 1u);   // round-to-nearest-even
    return (short)(u >> 16);
}

// async 16B/lane global->LDS; LDS dest = wave-uniform base + lane*16B.
__device__ __forceinline__ void gl_lds16(const short* g, short* l) {
    __builtin_amdgcn_global_load_lds(
        (const __attribute__((address_space(1))) unsigned int*)g,
        (__attribute__((address_space(3))) unsigned int*)l,
        16, 0, 0);
}

// single fp32->bf16 conversion pass over x, Wi, Wo (8 elems/thread)
__global__ __launch_bounds__(256) void cvt_all(
    const float* __restrict__ x, const float* __restrict__ Wi,
    const float* __restrict__ Wo, short* __restrict__ xb,
    short* __restrict__ Wib, short* __restrict__ Wob)
{
    constexpr int n1 = 16384 * 1024 / 8;
    constexpr int n2 = 2048 * 1024 / 8;
    constexpr int n3 = 1024 * 1024 / 8;
    int i = blockIdx.x * 256 + threadIdx.x;
    const float* src;
    short* dst;
    int j;
    if (i < n1)           { src = x;  dst = xb;  j = i; }
    else if (i < n1 + n2) { src = Wi; dst = Wib; j = i - n1; }
    else if (i < n1 + n2 + n3) { src = Wo; dst = Wob; j = i - n1 - n2; }
    else return;
    float4 a = ((const float4*)src)[2 * j];
    float4 b = ((const float4*)src)[2 * j + 1];
    short8 o;
    o[0] = f2b(a.x); o[1] = f2b(a.y); o[2] = f2b(a.z); o[3] = f2b(a.w);
    o[4] = f2b(b.x); o[5] = f2b(b.y); o[6] = f2b(b.z); o[7] = f2b(b.w);
    ((short8*)dst)[j] = o;
}

// One K-tile.  SLOT/NSLOT/P/NP are literals; WAIT = vmcnt immediate string;
// ST = tile to stage (-1 none); PREF = prefetch next tile's (bvv,a0).
#define GB_TILE(SLOT, NSLOT, P, NP, WAIT, ST, PREF)                           \
  {                                                                           \
    asm volatile(WAIT ::: "memory");                                          \
    __builtin_amdgcn_s_barrier();                                             \
    asm volatile("" ::: "memory");                                            \
    if ((ST) >= 0) {                                                          \
        gl_lds16(gA + (size_t)(ST) * 32, lA0 + ((ST) & 3) * 8192);            \
        gl_lds16(gA + (size_t)(ST) * 32 + (size_t)16 * lda,                   \
                 lA0 + ((ST) & 3) * 8192 + 512);                              \
    }                                                                         \
    short8 a1_[4];                                                            \
    _Pragma("unroll") for (int mi = 0; mi < 4; mi++)                          \
        a1_[mi] = *(const short8*)&As[(SLOT) * 8192 + aBase + (4 + mi) * 512];\
    __builtin_amdgcn_s_setprio(1);                                            \
    _Pragma("unroll") for (int mi = 0; mi < 4; mi++)                          \
      _Pragma("unroll") for (int ni = 0; ni < 4; ni++)                        \
        acc[mi][ni] = __builtin_amdgcn_mfma_f32_16x16x32_bf16(                \
            a0[P][mi], bvv[P][ni], acc[mi][ni], 0, 0, 0);                     \
    __builtin_amdgcn_s_setprio(0);                                            \
    if ((ST) >= 0) {                                                          \
        gl_lds16(gB + (size_t)(ST) * 32, lB0 + ((ST) & 3) * 8192);            \
        gl_lds16(gB + (size_t)(ST) * 32 + (size_t)16 * ldb,                   \
                 lB0 + ((ST) & 3) * 8192 + 512);                              \
    }                                                                         \
    if (PREF) {                                                               \
      _Pragma("unroll") for (int ni = 0; ni < 4; ni++)                        \
        bvv[NP][ni] = *(const short8*)&Bs[(NSLOT) * 8192 + bBase + ni * 512]; \
      _Pragma("unroll") for (int mi = 0; mi < 4; mi++)                        \
        a0[NP][mi] = *(const short8*)&As[(NSLOT) * 8192 + aBase + mi * 512];  \
    }                                                                         \
    __builtin_amdgcn_s_setprio(1);                                            \
    _Pragma("unroll") for (int mi = 0; mi < 4; mi++)                          \
      _Pragma("unroll") for (int ni = 0; ni < 4; ni++)                        \
        acc[4 + mi][ni] = __builtin_amdgcn_mfma_f32_16x16x32_bf16(            \
            a1_[mi], bvv[P][ni], acc[4 + mi][ni], 0, 0, 0);                   \
    __builtin_amdgcn_s_setprio(0);                                            \
  }

// C[m][n] = sum_k A[m][k]*B[n][k] + bias[n].  A,B bf16 (B row-major [N][K]).
// OUTF32: C fp32, else C bf16.  256x256 tile, BK=32, register-pipelined.
template <bool OUTF32>
__global__ __launch_bounds__(512, 2) void gemm_bt(
    const short* __restrict__ A, const short* __restrict__ B,
    const float* __restrict__ bias, void* __restrict__ Cv,
    int lda, int ldb, int ldc)
{
    // ring of 4 slots; each slot 256 rows x 32 shorts = 16 KB per operand.
    __shared__ __attribute__((aligned(16))) short As[4 * 8192];
    __shared__ __attribute__((aligned(16))) short Bs[4 * 8192];

    const int tid  = threadIdx.x;
    const int wave = tid >> 6;                 // 0..7
    const int lane = tid & 63;

    // T1: bijective XCD swizzle (nwg % 8 == 0 for both GEMMs).
    const int nwg = gridDim.x * gridDim.y;
    const int f   = blockIdx.y * gridDim.x + blockIdx.x;
    const int nf  = (f & 7) * (nwg >> 3) + (f >> 3);
    const int mBase = (nf / gridDim.x) * 256;
    const int nBase = (nf % gridDim.x) * 256;

    floatx4 acc[8][4];
#pragma unroll
    for (int i = 0; i < 8; i++)
#pragma unroll
        for (int j = 0; j < 4; j++) acc[i][j] = {0.f, 0.f, 0.f, 0.f};

    // staging: wave w owns rows [32w, 32w+32) of A and B.  2 instrs per
    // operand per tile (16 rows x 64B each).  lane -> row (lane>>2), dest
    // group (lane&3); source group = dest ^ ((row>>1)&3)  [pre-swizzle].
    const int srow = lane >> 2;                // 0..15
    const int sg   = ((lane & 3) ^ ((srow >> 1) & 3)) * 8;
    const short* gA = A + (size_t)(mBase + wave * 32 + srow) * lda + sg;
    const short* gB = B + (size_t)(nBase + wave * 32 + srow) * ldb + sg;
    short* lA0 = &As[wave * 1024];             // rows 32w.. of slot 0
    short* lB0 = &Bs[wave * 1024];

    // fragments: wave (wm = wave>>2, wn = wave&3) owns a 128x64 C panel.
    const int fRow = lane & 15;
    const int lg   = lane >> 4;                // k-group 0..3
    const int pg8  = (lg ^ ((fRow >> 1) & 3)) * 8;
    const int mq   = (wave >> 2) * 128;
    const int nq   = (wave & 3) * 64;
    const int aBase = (mq + fRow) * 32 + pg8;
    const int bBase = (nq + fRow) * 32 + pg8;

    // double-buffered fragment registers (all indices compile-time).
    short8 bvv[2][4], a0[2][4];

    // prologue: stage tiles 0..2 (12 loads), wait tile 0, read its ph0 frags.
#pragma unroll
    for (int p = 0; p < 3; p++) {
        gl_lds16(gA + (size_t)p * 32, lA0 + p * 8192);
        gl_lds16(gA + (size_t)p * 32 + (size_t)16 * lda, lA0 + p * 8192 + 512);
        gl_lds16(gB + (size_t)p * 32, lB0 + p * 8192);
        gl_lds16(gB + (size_t)p * 32 + (size_t)16 * ldb, lB0 + p * 8192 + 512);
    }
    asm volatile("s_waitcnt vmcnt(8)" ::: "memory");
    __builtin_amdgcn_s_barrier();
    asm volatile("" ::: "memory");
#pragma unroll
    for (int ni = 0; ni < 4; ni++)
        bvv[0][ni] = *(const short8*)&Bs[bBase + ni * 512];
#pragma unroll
    for (int mi = 0; mi < 4; mi++)
        a0[0][mi] = *(const short8*)&As[aBase + mi * 512];

    // main: t = 0..27 (stage t+3, prefetch t+1 frags).
    for (int tb = 0; tb < 28; tb += 4) {
        GB_TILE(0, 1, 0, 1, "s_waitcnt vmcnt(4)", tb + 3, 1)
        GB_TILE(1, 2, 1, 0, "s_waitcnt vmcnt(4)", tb + 4, 1)
        GB_TILE(2, 3, 0, 1, "s_waitcnt vmcnt(4)", tb + 5, 1)
        GB_TILE(3, 0, 1, 0, "s_waitcnt vmcnt(4)", tb + 6, 1)
    }
    // tail: t = 28 (stages 31), 29, 30 (vmcnt0 so t31 frags readable), 31.
    GB_TILE(0, 1, 0, 1, "s_waitcnt vmcnt(4)", 31, 1)
    GB_TILE(1, 2, 1, 0, "s_waitcnt vmcnt(4)", -1, 1)
    GB_TILE(2, 3, 0, 1, "s_waitcnt vmcnt(0)", -1, 1)
    GB_TILE(3, 0, 1, 0, "s_waitcnt vmcnt(0)", -1, 0)

    // C/D layout: col = lane&15, row = (lane>>4)*4 + reg   [m89/m91-verified]
    const int colq = lane & 15;
    const int rowq = lg * 4;
#pragma unroll
    for (int ni = 0; ni < 4; ni++) {
        const int col = nBase + nq + ni * 16 + colq;
        const float bsv = bias[col];
#pragma unroll
        for (int mi = 0; mi < 8; mi++) {
            const int row = mBase + mq + mi * 16 + rowq;
#pragma unroll
            for (int r = 0; r < 4; r++) {
                float v = acc[mi][ni][r] + bsv;
                if (OUTF32)
                    ((float*)Cv)[(size_t)(row + r) * ldc + col] = v;
                else
                    ((short*)Cv)[(size_t)(row + r) * ldc + col] = f2b(v);
            }
        }
    }
}

// y[m][d] = silu( v[m-1]*w0 + v[m]*w1 + v[m+1]*w2 + bc ) * u[m][d]
// uv bf16 [16384][2048] (u cols 0..1023, v cols 1024..2047); Wc/bc fp32;
// y written bf16 to yb [16384][1024]. 8 channels per thread.
__global__ __launch_bounds__(256) void conv_gate(
    const short* __restrict__ uv, const float* __restrict__ Wc,
    const float* __restrict__ bc, short* __restrict__ yb)
{
    const int idx = blockIdx.x * 256 + threadIdx.x;
    const int d8 = idx & 127;
    const int m  = idx >> 7;
    const int l  = m & 4095;             // L = 4096, zero-pad at batch edges
    const int d  = d8 * 8;

    float w[24];
#pragma unroll
    for (int q = 0; q < 6; q++)
        *(float4*)&w[q * 4] = ((const float4*)(Wc + d * 3))[q];
    float bcv[8];
    *(float4*)&bcv[0] = ((const float4*)(bc + d))[0];
    *(float4*)&bcv[4] = ((const float4*)(bc + d))[1];

    const size_t rowu = (size_t)m * 2048 + d;
    const size_t rowv = rowu + 1024;

    const short8 z = {0, 0, 0, 0, 0, 0, 0, 0};
    const short8 us = *(const short8*)(uv + rowu);
    const short8 vc = *(const short8*)(uv + rowv);
    const short8 vm = (l > 0)    ? *(const short8*)(uv + rowv - 2048) : z;
    const short8 vp = (l < 4095) ? *(const short8*)(uv + rowv + 2048) : z;

    short8 outv;
#pragma unroll
    for (int j = 0; j < 8; j++) {
        float y = b2f(vm[j]) * w[j * 3 + 0]
                + b2f(vc[j]) * w[j * 3 + 1]
                + b2f(vp[j]) * w[j * 3 + 2]
                + bcv[j];
        float sil = y / (1.0f + expf(-y));
        outv[j] = f2b(sil * b2f(us[j]));
    }
    *(short8*)(yb + (size_t)m * 1024 + d) = outv;
}

extern "C" void kernel_launch(void* const* d_in, const int* in_sizes, int n_in,
                              void* d_out, int out_size, void* d_ws, size_t ws_size,
                              hipStream_t stream)
{
    const float* x  = (const float*)d_in[0];   // [4,4096,1024]
    const float* Wi = (const float*)d_in[1];   // [2048,1024]
    const float* bi = (const float*)d_in[2];   // [2048]
    const float* Wc = (const float*)d_in[3];   // [1024,1,3]
    const float* bc = (const float*)d_in[4];   // [1024]
    const float* Wo = (const float*)d_in[5];   // [1024,1024]
    const float* bo = (const float*)d_in[6];   // [1024]
    float* out = (float*)d_out;                // [4,4096,1024] fp32

    short* wsS = (short*)d_ws;
    short* uv  = wsS;                          // 16384*2048
    short* xb  = uv + (size_t)16384 * 2048;    // 16384*1024 (later: yb)
    short* Wib = xb + (size_t)16384 * 1024;    // 2048*1024
    short* Wob = Wib + (size_t)2048 * 1024;    // 1024*1024

    dim3 blk(256);
    dim3 blkG(512);

    // one fused bf16 conversion pass (x, Wi, Wo)
    constexpr int nCvt = (16384 * 1024 + 2048 * 1024 + 1024 * 1024) / 8;
    cvt_all<<<(nCvt + 255) / 256, blk, 0, stream>>>(x, Wi, Wo, xb, Wib, Wob);

    // GEMM1: uv = xb @ Wib^T + bi   (M=16384, N=2048, K=1024), bf16 out
    dim3 g1(2048 / 256, 16384 / 256);          // (8, 64) = 512 blocks
    gemm_bt<false><<<g1, blkG, 0, stream>>>(xb, Wib, bi, uv, 1024, 1024, 2048);

    // conv + silu gate -> yb (reuses xb region; xb dead after GEMM1)
    conv_gate<<<(16384 * 128) / 256, blk, 0, stream>>>(uv, Wc, bc, xb);

    // GEMM2: out = yb @ Wob^T + bo  (M=16384, N=1024, K=1024), fp32 out
    dim3 g2(1024 / 256, 16384 / 256);          // (4, 64) = 256 blocks
    gemm_bt<true><<<g2, blkG, 0, stream>>>(xb, Wob, bo, out, 1024, 1024, 1024);
}

// Round 4
// 291.253 us; speedup vs baseline: 1.0282x; 1.0282x over previous
//
#include <hip/hip_runtime.h>
#include <math.h>

// MambaBlock, fp32 in/out, bf16 MFMA compute.
// uv = x @ Wi^T + bi ; u,v = split(uv) ; y = silu(dwconv3(v)+bc)*u ; out = y @ Wo^T + bo
// B=4, L=4096, D=1024 -> M = 16384 rows; GEMM1 N=2048, GEMM2 N=1024, K=1024.
//
// GEMM v5 (template-faithful phases): 256x256 tile, BK=32, 512 threads
// (8 waves, 2M x 4N), ring of 4 LDS slots (128 KiB), 2-tile lookahead,
// counted vmcnt(8) once per tile.  Each K-tile = 2 phases; PHASE SHAPE IS
// THE m201 TEMPLATE'S:
//     ds_reads (this phase's frags) ; stage (2 gl_lds) ; sched_barrier
//     s_barrier                      <- read latency hides under the barrier
//     lgkmcnt(0) ; sched_barrier     <- data ready; previous phase's MFMAs
//     setprio(1) 16xMFMA setprio(0)     still draining the matrix pipe
//     s_barrier
// R2/R3 issued reads AFTER the leading barrier with lgkmcnt(0) immediately
// following -> zero covering distance -> LDS and MFMA strictly alternated
// (25-31% MfmaUtil).  Here every phase's reads get [stage+barrier+drain] of
// covering distance, itself covered by the previous phase's MFMA drain.
//
// vmcnt ledger (4 loads/tile: A2 in ph0, B2 in ph1): entering tile t the
// outstanding set is {t+1, t+2} = 8; ph0 stages A(t+3) -> 10; ph1 stages
// B(t+3) -> 12; vmcnt(8) retires tile t+1's loads (needed by tile t+1 ph0
// reads, one tile early).  Tail: 8 -> 4 -> 0.  Slot (t+3)&3 staged at tile t
// was last read at tile t-1 (lgkm0 before those MFMAs -> drained before the
// trailing barrier all waves crossed).
//
// LDS swizzle (64B rows, 4x16B groups): logical group g of row r at physical
// g ^ ((r>>1)&3); staging pre-swizzles the GLOBAL source address (linear LDS
// dest for global_load_lds), ds_read applies the same XOR.  Bank conflicts
// measured 0 in R2/R3.  T1 bijective XCD swizzle kept (FETCH 137->49 MB).

typedef __attribute__((ext_vector_type(8))) short short8;
typedef __attribute__((ext_vector_type(4))) float floatx4;

__device__ __forceinline__ float b2f(short s) {
    unsigned int u = ((unsigned int)(unsigned short)s) << 16;
    float f;
    __builtin_memcpy(&f, &u, 4);
    return f;
}

__device__ __forceinline__ short f2b(float f) {
    unsigned int u;
    __builtin_memcpy(&u, &f, 4);
    u += 0x7fffu + ((u >> 16) & 1u);   // round-to-nearest-even
    return (short)(u >> 16);
}

// async 16B/lane global->LDS; LDS dest = wave-uniform base + lane*16B.
__device__ __forceinline__ void gl_lds16(const short* g, short* l) {
    __builtin_amdgcn_global_load_lds(
        (const __attribute__((address_space(1))) unsigned int*)g,
        (__attribute__((address_space(3))) unsigned int*)l,
        16, 0, 0);
}

// single fp32->bf16 conversion pass over x, Wi, Wo (8 elems/thread)
__global__ __launch_bounds__(256) void cvt_all(
    const float* __restrict__ x, const float* __restrict__ Wi,
    const float* __restrict__ Wo, short* __restrict__ xb,
    short* __restrict__ Wib, short* __restrict__ Wob)
{
    constexpr int n1 = 16384 * 1024 / 8;
    constexpr int n2 = 2048 * 1024 / 8;
    constexpr int n3 = 1024 * 1024 / 8;
    int i = blockIdx.x * 256 + threadIdx.x;
    const float* src;
    short* dst;
    int j;
    if (i < n1)           { src = x;  dst = xb;  j = i; }
    else if (i < n1 + n2) { src = Wi; dst = Wib; j = i - n1; }
    else if (i < n1 + n2 + n3) { src = Wo; dst = Wob; j = i - n1 - n2; }
    else return;
    float4 a = ((const float4*)src)[2 * j];
    float4 b = ((const float4*)src)[2 * j + 1];
    short8 o;
    o[0] = f2b(a.x); o[1] = f2b(a.y); o[2] = f2b(a.z); o[3] = f2b(a.w);
    o[4] = f2b(b.x); o[5] = f2b(b.y); o[6] = f2b(b.z); o[7] = f2b(b.w);
    ((short8*)dst)[j] = o;
}

// One K-tile, two template-shaped phases.  SLOT/S3 literal; WAIT = vmcnt
// immediate for this tile (placed in ph1); ST = tile to stage (-1 none).
#define GB_TILE(SLOT, S3, WAIT, ST)                                           \
  {                                                                           \
    short8 bvv[4], a0[4];                                                     \
    _Pragma("unroll") for (int ni = 0; ni < 4; ni++)                          \
        bvv[ni] = *(const short8*)&Bs[(SLOT) * 8192 + bBase + ni * 512];      \
    _Pragma("unroll") for (int mi = 0; mi < 4; mi++)                          \
        a0[mi] = *(const short8*)&As[(SLOT) * 8192 + aBase + mi * 512];       \
    if ((ST) >= 0) {                                                          \
        gl_lds16(gA + (size_t)(ST) * 32, lA0 + (S3) * 8192);                  \
        gl_lds16(gA + (size_t)(ST) * 32 + (size_t)16 * lda,                   \
                 lA0 + (S3) * 8192 + 512);                                    \
    }                                                                         \
    __builtin_amdgcn_sched_barrier(0);                                        \
    __builtin_amdgcn_s_barrier();                                             \
    asm volatile("s_waitcnt lgkmcnt(0)" ::: "memory");                        \
    __builtin_amdgcn_sched_barrier(0);                                        \
    __builtin_amdgcn_s_setprio(1);                                            \
    _Pragma("unroll") for (int mi = 0; mi < 4; mi++)                          \
      _Pragma("unroll") for (int ni = 0; ni < 4; ni++)                        \
        acc[mi][ni] = __builtin_amdgcn_mfma_f32_16x16x32_bf16(                \
            a0[mi], bvv[ni], acc[mi][ni], 0, 0, 0);                           \
    __builtin_amdgcn_s_setprio(0);                                            \
    __builtin_amdgcn_s_barrier();                                             \
    short8 a1[4];                                                             \
    _Pragma("unroll") for (int mi = 0; mi < 4; mi++)                          \
        a1[mi] = *(const short8*)&As[(SLOT) * 8192 + aBase + (4 + mi) * 512]; \
    if ((ST) >= 0) {                                                          \
        gl_lds16(gB + (size_t)(ST) * 32, lB0 + (S3) * 8192);                  \
        gl_lds16(gB + (size_t)(ST) * 32 + (size_t)16 * ldb,                   \
                 lB0 + (S3) * 8192 + 512);                                    \
    }                                                                         \
    asm volatile(WAIT ::: "memory");                                          \
    __builtin_amdgcn_sched_barrier(0);                                        \
    __builtin_amdgcn_s_barrier();                                             \
    asm volatile("s_waitcnt lgkmcnt(0)" ::: "memory");                        \
    __builtin_amdgcn_sched_barrier(0);                                        \
    __builtin_amdgcn_s_setprio(1);                                            \
    _Pragma("unroll") for (int mi = 0; mi < 4; mi++)                          \
      _Pragma("unroll") for (int ni = 0; ni < 4; ni++)                        \
        acc[4 + mi][ni] = __builtin_amdgcn_mfma_f32_16x16x32_bf16(            \
            a1[mi], bvv[ni], acc[4 + mi][ni], 0, 0, 0);                       \
    __builtin_amdgcn_s_setprio(0);                                            \
    __builtin_amdgcn_s_barrier();                                             \
  }

// C[m][n] = sum_k A[m][k]*B[n][k] + bias[n].  A,B bf16 (B row-major [N][K]).
// OUTF32: C fp32, else C bf16.  256x256 tile, BK=32, template-phase pipeline.
template <bool OUTF32>
__global__ __launch_bounds__(512, 2) void gemm_bt(
    const short* __restrict__ A, const short* __restrict__ B,
    const float* __restrict__ bias, void* __restrict__ Cv,
    int lda, int ldb, int ldc)
{
    // ring of 4 slots; each slot 256 rows x 32 shorts = 16 KB per operand.
    __shared__ __attribute__((aligned(16))) short As[4 * 8192];
    __shared__ __attribute__((aligned(16))) short Bs[4 * 8192];

    const int tid  = threadIdx.x;
    const int wave = tid >> 6;                 // 0..7
    const int lane = tid & 63;

    // T1: bijective XCD swizzle (nwg % 8 == 0 for both GEMMs).
    const int nwg = gridDim.x * gridDim.y;
    const int f   = blockIdx.y * gridDim.x + blockIdx.x;
    const int nf  = (f & 7) * (nwg >> 3) + (f >> 3);
    const int mBase = (nf / gridDim.x) * 256;
    const int nBase = (nf % gridDim.x) * 256;

    floatx4 acc[8][4];
#pragma unroll
    for (int i = 0; i < 8; i++)
#pragma unroll
        for (int j = 0; j < 4; j++) acc[i][j] = {0.f, 0.f, 0.f, 0.f};

    // staging: wave w owns rows [32w, 32w+32) of A and B.  2 instrs per
    // operand per tile (16 rows x 64B each).  lane -> row (lane>>2), dest
    // group (lane&3); source group = dest ^ ((row>>1)&3)  [pre-swizzle].
    const int srow = lane >> 2;                // 0..15
    const int sg   = ((lane & 3) ^ ((srow >> 1) & 3)) * 8;
    const short* gA = A + (size_t)(mBase + wave * 32 + srow) * lda + sg;
    const short* gB = B + (size_t)(nBase + wave * 32 + srow) * ldb + sg;
    short* lA0 = &As[wave * 1024];             // rows 32w.. of slot 0
    short* lB0 = &Bs[wave * 1024];

    // fragments: wave (wm = wave>>2, wn = wave&3) owns a 128x64 C panel.
    const int fRow = lane & 15;
    const int lg   = lane >> 4;                // k-group 0..3
    const int pg8  = (lg ^ ((fRow >> 1) & 3)) * 8;
    const int mq   = (wave >> 2) * 128;
    const int nq   = (wave & 3) * 64;
    const int aBase = (mq + fRow) * 32 + pg8;
    const int bBase = (nq + fRow) * 32 + pg8;

    // prologue: stage tiles 0..2 (12 loads); retire tile 0; publish.
#pragma unroll
    for (int p = 0; p < 3; p++) {
        gl_lds16(gA + (size_t)p * 32, lA0 + p * 8192);
        gl_lds16(gA + (size_t)p * 32 + (size_t)16 * lda, lA0 + p * 8192 + 512);
        gl_lds16(gB + (size_t)p * 32, lB0 + p * 8192);
        gl_lds16(gB + (size_t)p * 32 + (size_t)16 * ldb, lB0 + p * 8192 + 512);
    }
    asm volatile("s_waitcnt vmcnt(8)" ::: "memory");
    __builtin_amdgcn_s_barrier();
    asm volatile("" ::: "memory");

    // main: tiles 0..27 (stage t+3); slots cycle 0..3.
    for (int tb = 0; tb < 28; tb += 4) {
        GB_TILE(0, 3, "s_waitcnt vmcnt(8)", tb + 3)
        GB_TILE(1, 0, "s_waitcnt vmcnt(8)", tb + 4)
        GB_TILE(2, 1, "s_waitcnt vmcnt(8)", tb + 5)
        GB_TILE(3, 2, "s_waitcnt vmcnt(8)", tb + 6)
    }
    // tail: t=28 stages 31; 29..31 drain 8 -> 4 -> 0.
    GB_TILE(0, 3, "s_waitcnt vmcnt(8)", 31)
    GB_TILE(1, 0, "s_waitcnt vmcnt(4)", -1)
    GB_TILE(2, 1, "s_waitcnt vmcnt(0)", -1)
    GB_TILE(3, 2, "s_waitcnt vmcnt(0)", -1)

    // C/D layout: col = lane&15, row = (lane>>4)*4 + reg   [m89/m91-verified]
    const int colq = lane & 15;
    const int rowq = lg * 4;
#pragma unroll
    for (int ni = 0; ni < 4; ni++) {
        const int col = nBase + nq + ni * 16 + colq;
        const float bsv = bias[col];
#pragma unroll
        for (int mi = 0; mi < 8; mi++) {
            const int row = mBase + mq + mi * 16 + rowq;
#pragma unroll
            for (int r = 0; r < 4; r++) {
                float v = acc[mi][ni][r] + bsv;
                if (OUTF32)
                    ((float*)Cv)[(size_t)(row + r) * ldc + col] = v;
                else
                    ((short*)Cv)[(size_t)(row + r) * ldc + col] = f2b(v);
            }
        }
    }
}

// y[m][d] = silu( v[m-1]*w0 + v[m]*w1 + v[m+1]*w2 + bc ) * u[m][d]
// uv bf16 [16384][2048] (u cols 0..1023, v cols 1024..2047); Wc/bc fp32;
// y written bf16 to yb [16384][1024]. 8 channels per thread.
__global__ __launch_bounds__(256) void conv_gate(
    const short* __restrict__ uv, const float* __restrict__ Wc,
    const float* __restrict__ bc, short* __restrict__ yb)
{
    const int idx = blockIdx.x * 256 + threadIdx.x;
    const int d8 = idx & 127;
    const int m  = idx >> 7;
    const int l  = m & 4095;             // L = 4096, zero-pad at batch edges
    const int d  = d8 * 8;

    float w[24];
#pragma unroll
    for (int q = 0; q < 6; q++)
        *(float4*)&w[q * 4] = ((const float4*)(Wc + d * 3))[q];
    float bcv[8];
    *(float4*)&bcv[0] = ((const float4*)(bc + d))[0];
    *(float4*)&bcv[4] = ((const float4*)(bc + d))[1];

    const size_t rowu = (size_t)m * 2048 + d;
    const size_t rowv = rowu + 1024;

    const short8 z = {0, 0, 0, 0, 0, 0, 0, 0};
    const short8 us = *(const short8*)(uv + rowu);
    const short8 vc = *(const short8*)(uv + rowv);
    const short8 vm = (l > 0)    ? *(const short8*)(uv + rowv - 2048) : z;
    const short8 vp = (l < 4095) ? *(const short8*)(uv + rowv + 2048) : z;

    short8 outv;
#pragma unroll
    for (int j = 0; j < 8; j++) {
        float y = b2f(vm[j]) * w[j * 3 + 0]
                + b2f(vc[j]) * w[j * 3 + 1]
                + b2f(vp[j]) * w[j * 3 + 2]
                + bcv[j];
        float sil = y / (1.0f + expf(-y));
        outv[j] = f2b(sil * b2f(us[j]));
    }
    *(short8*)(yb + (size_t)m * 1024 + d) = outv;
}

extern "C" void kernel_launch(void* const* d_in, const int* in_sizes, int n_in,
                              void* d_out, int out_size, void* d_ws, size_t ws_size,
                              hipStream_t stream)
{
    const float* x  = (const float*)d_in[0];   // [4,4096,1024]
    const float* Wi = (const float*)d_in[1];   // [2048,1024]
    const float* bi = (const float*)d_in[2];   // [2048]
    const float* Wc = (const float*)d_in[3];   // [1024,1,3]
    const float* bc = (const float*)d_in[4];   // [1024]
    const float* Wo = (const float*)d_in[5];   // [1024,1024]
    const float* bo = (const float*)d_in[6];   // [1024]
    float* out = (float*)d_out;                // [4,4096,1024] fp32

    short* wsS = (short*)d_ws;
    short* uv  = wsS;                          // 16384*2048
    short* xb  = uv + (size_t)16384 * 2048;    // 16384*1024 (later: yb)
    short* Wib = xb + (size_t)16384 * 1024;    // 2048*1024
    short* Wob = Wib + (size_t)2048 * 1024;    // 1024*1024

    dim3 blk(256);
    dim3 blkG(512);

    // one fused bf16 conversion pass (x, Wi, Wo)
    constexpr int nCvt = (16384 * 1024 + 2048 * 1024 + 1024 * 1024) / 8;
    cvt_all<<<(nCvt + 255) / 256, blk, 0, stream>>>(x, Wi, Wo, xb, Wib, Wob);

    // GEMM1: uv = xb @ Wib^T + bi   (M=16384, N=2048, K=1024), bf16 out
    dim3 g1(2048 / 256, 16384 / 256);          // (8, 64) = 512 blocks
    gemm_bt<false><<<g1, blkG, 0, stream>>>(xb, Wib, bi, uv, 1024, 1024, 2048);

    // conv + silu gate -> yb (reuses xb region; xb dead after GEMM1)
    conv_gate<<<(16384 * 128) / 256, blk, 0, stream>>>(uv, Wc, bc, xb);

    // GEMM2: out = yb @ Wob^T + bo  (M=16384, N=1024, K=1024), fp32 out
    dim3 g2(1024 / 256, 16384 / 256);          // (4, 64) = 256 blocks
    gemm_bt<true><<<g2, blkG, 0, stream>>>(xb, Wob, bo, out, 1024, 1024, 1024);
}

// Round 5
// 265.229 us; speedup vs baseline: 1.1291x; 1.0981x over previous
//
#include <hip/hip_runtime.h>
#include <math.h>

// MambaBlock, fp32 in/out, bf16 MFMA compute.
// uv = x @ Wi^T + bi ; u,v = split(uv) ; y = silu(dwconv3(v)+bc)*u ; out = y @ Wo^T + bo
// B=4, L=4096, D=1024 -> M = 16384 rows; GEMM1 N=2048, GEMM2 N=1024, K=1024.
//
// ws layout (bf16 shorts): uv[16384][2048] | xb[16384][1024] (reused as yb) |
// Wib[2048][1024] | Wob[1024][1024]  = 102 MiB total.
//
// GEMM: proven R0 structure (128x128 tile, BK=64, 16 k-iters, 2 barriers per
// k-iter, global_load_lds width-16 staging, XOR-swizzled 128B rows).  Four
// rounds of 256^2 deep-pipeline ports all measured 25-31% MfmaUtil (LDS and
// MFMA phases serialize; mechanism not localizable without disasm) -> per
// R3's pre-commit, reverted to this structure (77 us GEMM1, 892 TF = its
// documented ~900 TF structural ceiling).
// Added vs R0: T1 bijective XCD swizzle (f&7 -> XCD-contiguous block chunks),
// verified on R2-R4 to cut GEMM1 FETCH 137 MB -> 49 MB.  nwg%8==0 for both
// GEMM grids (2048, 1024 blocks).
//
// LDS XOR swizzle for 128B rows: logical 16B group g of row r at physical
// g ^ (r&7) -> ds_read_b128 8-lane service groups hit all 8 bank-slots.

typedef __attribute__((ext_vector_type(8))) short short8;
typedef __attribute__((ext_vector_type(4))) float floatx4;

__device__ __forceinline__ float b2f(short s) {
    unsigned int u = ((unsigned int)(unsigned short)s) << 16;
    float f;
    __builtin_memcpy(&f, &u, 4);
    return f;
}

__device__ __forceinline__ short f2b(float f) {
    unsigned int u;
    __builtin_memcpy(&u, &f, 4);
    u += 0x7fffu + ((u >> 16) & 1u);   // round-to-nearest-even
    return (short)(u >> 16);
}

// async 16B/lane global->LDS; LDS dest = wave-uniform base + lane*16B.
__device__ __forceinline__ void gl_lds16(const short* g, short* l) {
    __builtin_amdgcn_global_load_lds(
        (const __attribute__((address_space(1))) unsigned int*)g,
        (__attribute__((address_space(3))) unsigned int*)l,
        16, 0, 0);
}

// single fp32->bf16 conversion pass over x, Wi, Wo (8 elems/thread)
__global__ __launch_bounds__(256) void cvt_all(
    const float* __restrict__ x, const float* __restrict__ Wi,
    const float* __restrict__ Wo, short* __restrict__ xb,
    short* __restrict__ Wib, short* __restrict__ Wob)
{
    constexpr int n1 = 16384 * 1024 / 8;
    constexpr int n2 = 2048 * 1024 / 8;
    constexpr int n3 = 1024 * 1024 / 8;
    int i = blockIdx.x * 256 + threadIdx.x;
    const float* src;
    short* dst;
    int j;
    if (i < n1)           { src = x;  dst = xb;  j = i; }
    else if (i < n1 + n2) { src = Wi; dst = Wib; j = i - n1; }
    else if (i < n1 + n2 + n3) { src = Wo; dst = Wob; j = i - n1 - n2; }
    else return;
    float4 a = ((const float4*)src)[2 * j];
    float4 b = ((const float4*)src)[2 * j + 1];
    short8 o;
    o[0] = f2b(a.x); o[1] = f2b(a.y); o[2] = f2b(a.z); o[3] = f2b(a.w);
    o[4] = f2b(b.x); o[5] = f2b(b.y); o[6] = f2b(b.z); o[7] = f2b(b.w);
    ((short8*)dst)[j] = o;
}

// C[m][n] = sum_k A[m][k]*B[n][k] + bias[n].  A,B bf16 (B row-major [N][K]).
// OUTF32: C fp32, else C bf16. 128x128 tile, BK=64, 4 waves of 4x4 16x16x32
// MFMA (two k-halves per iter).
template <bool OUTF32>
__global__ __launch_bounds__(256, 3) void gemm_bt(
    const short* __restrict__ A, const short* __restrict__ B,
    const float* __restrict__ bias, void* __restrict__ Cv,
    int lda, int ldb, int ldc)
{
    constexpr int K = 1024;
    __shared__ __attribute__((aligned(16))) short As[128 * 64];
    __shared__ __attribute__((aligned(16))) short Bs[128 * 64];

    const int tid  = threadIdx.x;
    const int wave = tid >> 6;
    const int lane = tid & 63;

    // T1: bijective XCD swizzle (nwg % 8 == 0 for both GEMM grids).
    // nf = (f mod 8)*(nwg/8) + f/8 gives XCD k a contiguous chunk of the
    // row-major block ordering -> B-panel subset stays L2-resident per XCD,
    // A served via L3.  Measured on R2-R4: FETCH 137 MB -> 49 MB.
    const int nwg = gridDim.x * gridDim.y;
    const int f   = blockIdx.y * gridDim.x + blockIdx.x;
    const int nf  = (f & 7) * (nwg >> 3) + (f >> 3);
    const int mBase = (nf / gridDim.x) * 128;
    const int nBase = (nf % gridDim.x) * 128;

    floatx4 acc[4][4];
#pragma unroll
    for (int i = 0; i < 4; i++)
#pragma unroll
        for (int j = 0; j < 4; j++) acc[i][j] = {0.f, 0.f, 0.f, 0.f};

    // staging (BK=64): wave w stages rows [32w,32w+32) of A and B as 4 async
    // instrs each (1KB = 8 rows x 128B per instr). lane -> row +(lane>>3),
    // source 16B group (lane&7) ^ ((lane>>3)&7)  [dest group lane&7 => the
    // XOR-swizzle: logical g at physical g ^ (row&7); base rows are 8-aligned].
    const int sRow = wave * 32 + (lane >> 3);
    const int sg   = (((lane & 7) ^ ((lane >> 3) & 7))) * 8;
    const short* gA = A + (size_t)(mBase + sRow) * lda + sg;
    const short* gB = B + (size_t)(nBase + sRow) * ldb + sg;
    short* lA = &As[(wave * 32) * 64];
    short* lB = &Bs[(wave * 32) * 64];

    const int mq = (wave & 1) * 64;
    const int nq = (wave >> 1) * 64;
    const int fRow = lane & 15;          // m (or n) within a 16-tile
    const int lg   = lane >> 4;          // logical 8-elem k-group (0..3) in a half
    // physical group offset for k-half 0; half 1 is p0 ^ 32 (shorts)
    const int p0   = ((lg ^ (fRow & 7))) * 8;

    for (int k0 = 0; k0 < K; k0 += 64) {
        __syncthreads();                       // previous tile fully consumed
#pragma unroll
        for (int j = 0; j < 4; j++) {
            gl_lds16(gA + (size_t)(8 * j) * lda + k0, lA + 8 * j * 64);
            gl_lds16(gB + (size_t)(8 * j) * ldb + k0, lB + 8 * j * 64);
        }
        __syncthreads();                       // drains vmcnt(0) before barrier

#pragma unroll
        for (int h = 0; h < 2; h++) {
            const int po = p0 ^ (h * 32);
            short8 a[4], b[4];
#pragma unroll
            for (int mi = 0; mi < 4; mi++)
                a[mi] = *(const short8*)&As[(mq + mi * 16 + fRow) * 64 + po];
#pragma unroll
            for (int ni = 0; ni < 4; ni++)
                b[ni] = *(const short8*)&Bs[(nq + ni * 16 + fRow) * 64 + po];
#pragma unroll
            for (int mi = 0; mi < 4; mi++)
#pragma unroll
                for (int ni = 0; ni < 4; ni++)
                    acc[mi][ni] = __builtin_amdgcn_mfma_f32_16x16x32_bf16(
                        a[mi], b[ni], acc[mi][ni], 0, 0, 0);
        }
    }

    // C/D layout: col = lane&15, row = (lane>>4)*4 + reg   [m89/m91-verified]
    const int colq = lane & 15;
    const int rowq = (lane >> 4) * 4;
#pragma unroll
    for (int ni = 0; ni < 4; ni++) {
        const int col = nBase + nq + ni * 16 + colq;
        const float bv = bias[col];
#pragma unroll
        for (int mi = 0; mi < 4; mi++) {
            const int row = mBase + mq + mi * 16 + rowq;
#pragma unroll
            for (int r = 0; r < 4; r++) {
                float v = acc[mi][ni][r] + bv;
                if (OUTF32)
                    ((float*)Cv)[(size_t)(row + r) * ldc + col] = v;
                else
                    ((short*)Cv)[(size_t)(row + r) * ldc + col] = f2b(v);
            }
        }
    }
}

// y[m][d] = silu( v[m-1]*w0 + v[m]*w1 + v[m+1]*w2 + bc ) * u[m][d]
// uv bf16 [16384][2048] (u cols 0..1023, v cols 1024..2047); Wc/bc fp32;
// y written bf16 to yb [16384][1024]. 8 channels per thread.
__global__ __launch_bounds__(256) void conv_gate(
    const short* __restrict__ uv, const float* __restrict__ Wc,
    const float* __restrict__ bc, short* __restrict__ yb)
{
    const int idx = blockIdx.x * 256 + threadIdx.x;
    const int d8 = idx & 127;
    const int m  = idx >> 7;
    const int l  = m & 4095;             // L = 4096, zero-pad at batch edges
    const int d  = d8 * 8;

    float w[24];
#pragma unroll
    for (int q = 0; q < 6; q++)
        *(float4*)&w[q * 4] = ((const float4*)(Wc + d * 3))[q];
    float bcv[8];
    *(float4*)&bcv[0] = ((const float4*)(bc + d))[0];
    *(float4*)&bcv[4] = ((const float4*)(bc + d))[1];

    const size_t rowu = (size_t)m * 2048 + d;
    const size_t rowv = rowu + 1024;

    const short8 z = {0, 0, 0, 0, 0, 0, 0, 0};
    const short8 us = *(const short8*)(uv + rowu);
    const short8 vc = *(const short8*)(uv + rowv);
    const short8 vm = (l > 0)    ? *(const short8*)(uv + rowv - 2048) : z;
    const short8 vp = (l < 4095) ? *(const short8*)(uv + rowv + 2048) : z;

    short8 outv;
#pragma unroll
    for (int j = 0; j < 8; j++) {
        float y = b2f(vm[j]) * w[j * 3 + 0]
                + b2f(vc[j]) * w[j * 3 + 1]
                + b2f(vp[j]) * w[j * 3 + 2]
                + bcv[j];
        float sil = y / (1.0f + expf(-y));
        outv[j] = f2b(sil * b2f(us[j]));
    }
    *(short8*)(yb + (size_t)m * 1024 + d) = outv;
}

extern "C" void kernel_launch(void* const* d_in, const int* in_sizes, int n_in,
                              void* d_out, int out_size, void* d_ws, size_t ws_size,
                              hipStream_t stream)
{
    const float* x  = (const float*)d_in[0];   // [4,4096,1024]
    const float* Wi = (const float*)d_in[1];   // [2048,1024]
    const float* bi = (const float*)d_in[2];   // [2048]
    const float* Wc = (const float*)d_in[3];   // [1024,1,3]
    const float* bc = (const float*)d_in[4];   // [1024]
    const float* Wo = (const float*)d_in[5];   // [1024,1024]
    const float* bo = (const float*)d_in[6];   // [1024]
    float* out = (float*)d_out;                // [4,4096,1024] fp32

    short* wsS = (short*)d_ws;
    short* uv  = wsS;                          // 16384*2048
    short* xb  = uv + (size_t)16384 * 2048;    // 16384*1024 (later: yb)
    short* Wib = xb + (size_t)16384 * 1024;    // 2048*1024
    short* Wob = Wib + (size_t)2048 * 1024;    // 1024*1024

    dim3 blk(256);

    // one fused bf16 conversion pass (x, Wi, Wo)
    constexpr int nCvt = (16384 * 1024 + 2048 * 1024 + 1024 * 1024) / 8;
    cvt_all<<<(nCvt + 255) / 256, blk, 0, stream>>>(x, Wi, Wo, xb, Wib, Wob);

    // GEMM1: uv = xb @ Wib^T + bi   (M=16384, N=2048, K=1024), bf16 out
    dim3 g1(2048 / 128, 16384 / 128);          // (16, 128) = 2048 blocks
    gemm_bt<false><<<g1, blk, 0, stream>>>(xb, Wib, bi, uv, 1024, 1024, 2048);

    // conv + silu gate -> yb (reuses xb region; xb dead after GEMM1)
    conv_gate<<<(16384 * 128) / 256, blk, 0, stream>>>(uv, Wc, bc, xb);

    // GEMM2: out = yb @ Wob^T + bo  (M=16384, N=1024, K=1024), fp32 out
    dim3 g2(1024 / 128, 16384 / 128);          // (8, 128) = 1024 blocks
    gemm_bt<true><<<g2, blk, 0, stream>>>(xb, Wob, bo, out, 1024, 1024, 1024);
}